// Round 10
// baseline (186.886 us; speedup 1.0000x reference)
//
#include <hip/hip_runtime.h>

// Shapes: genes[32][2048][4], smiles[32][2048][1024], w_ngf[4], w_genes[2048][512],
//         b_genes[512], w_smiles[1024][512], b_smiles[512], v[512] -> out[32][1024]

typedef __bf16 bf16_t;
typedef bf16_t bf16x8 __attribute__((ext_vector_type(8)));
typedef float f32x4 __attribute__((ext_vector_type(4)));

__device__ __forceinline__ unsigned short f32_to_bf16_rne(float f) {
    unsigned int u = __builtin_bit_cast(unsigned int, f);
    u = (u + 0x7FFFu + ((u >> 16) & 1u)) >> 16;
    return (unsigned short)u;
}

__device__ __forceinline__ float fast_tanh(float x) {
    float cx = fminf(fmaxf(x, -30.f), 30.f);
    float e = __expf(2.f * cx);
    return (e - 1.f) / (e + 1.f);
}

__device__ __forceinline__ float f16b2f(unsigned short v) {
    _Float16 h = __builtin_bit_cast(_Float16, v);
    return (float)h;
}

// K0b: pack w_smiles [1024][512] f32 into FRAGMENT-MAJOR bf16 (16x16 frags).
// Bp[frag=atile*32+gks][lane][e] = w[gks*32 + (lane>>4)*8 + e][atile*16 + (lane&15)]
__global__ void k0b_pack(const float* __restrict__ w, unsigned short* __restrict__ Bp) {
    int bid  = blockIdx.x;        // 1024 = 32 atiles * 32 gks
    int lane = threadIdx.x;       // 64
    int atile = bid >> 5, gks = bid & 31;
    int col = atile * 16 + (lane & 15);
    int k0  = gks * 32 + (lane >> 4) * 8;
    unsigned short us[8];
#pragma unroll
    for (int e = 0; e < 8; ++e)
        us[e] = f32_to_bf16_rne(w[(size_t)(k0 + e) * 512 + col]);
    *(uint4*)(Bp + (size_t)bid * 512 + lane * 8) = *(const uint4*)us;
}

// K1a: gc[b][g] = dot(genes[b][g][0..3], w_ngf)
__global__ void k1a_gc(const float4* __restrict__ genes, const float* __restrict__ wngf,
                       float* __restrict__ gc) {
    int i = blockIdx.x * 256 + threadIdx.x;   // 65536 = 32*2048
    float4 g = genes[i];
    gc[i] = g.x * wngf[0] + g.y * wngf[1] + g.z * wngf[2] + g.w * wngf[3];
}

// K1b: x[b][a] += sum_{g in chunk} gc[b][g] * w_genes[g][a]   (x pre-zeroed)
__global__ void k1b_x(const float* __restrict__ gc, const float* __restrict__ wg,
                      float* __restrict__ x) {
    __shared__ float gcl[256];
    int bx = blockIdx.x;              // 512 = 32 b * 2 a-halves * 8 g-chunks
    int b = bx >> 4, ah = (bx >> 3) & 1, gch = bx & 7;
    int g0 = gch * 256;
    gcl[threadIdx.x] = gc[b * 2048 + g0 + threadIdx.x];
    __syncthreads();
    int a = ah * 256 + threadIdx.x;
    float s = 0.f;
#pragma unroll 8
    for (int g = 0; g < 256; ++g) s += gcl[g] * wg[(size_t)(g0 + g) * 512 + a];
    atomicAdd(&x[b * 512 + a], s);
}

// K2: fused GEMM + tanh + dot(v) -> scores.  R3/R9 K-loop schedule, plus an
// f16 side-product copy of smiles (s16) written from the staged registers.
// Ordering inside the tile: CONVWRITE (pa/pb die) THEN STORE16 (st die) keeps
// the transient register watermark at 24 — same as R9.
__global__ __launch_bounds__(512, 4) void k2_scores(
    const float* __restrict__ smiles,
    const unsigned short* __restrict__ Bp,
    const float* __restrict__ xraw,
    const float* __restrict__ b_genes,
    const float* __restrict__ b_smiles,
    const float* __restrict__ v,
    float* __restrict__ scores,
    unsigned short* __restrict__ s16)
{
    __shared__ unsigned short A_lds[2 * 64 * 128];   // 32 KB, XOR-swizzled 256B rows
    __shared__ float score_lds[64];
    const int tid  = threadIdx.x;
    const int wave = tid >> 6;
    const int lane = tid & 63;
    const int l15  = lane & 15;
    const int l4   = lane >> 4;
    const int gm0  = blockIdx.x * 64;            // 1024 blocks
    const int bidx = gm0 >> 11;
    const int wbase = wave * 64;

    // wave's packed-B base: fragments (wave*4+nt)*32 + gks, each 1KB
    const unsigned short* bpp = Bp + (size_t)(wave * 128) * 512 + lane * 8;

    // staging geometry: thread owns 16 consecutive floats of the 64x128 tile
    const int srow = tid >> 3;                   // 0..63
    const float* sptr = smiles + (size_t)(gm0 + srow) * 1024 + (tid & 7) * 16;
    unsigned short* s16p = s16 ? s16 + (size_t)(gm0 + srow) * 1024 + (tid & 7) * 16
                               : (unsigned short*)0;
    const int sswz = (srow & 7) << 4;
    char* wr0 = (char*)A_lds + srow * 256 + (((tid & 7) * 32) ^ sswz);
    char* wr1 = (char*)A_lds + srow * 256 + ((((tid & 7) * 32) + 16) ^ sswz);

    if (tid < 64) score_lds[tid] = 0.f;

    float4 st0, st1, st2, st3;

    const f32x4 zero4 = {0.f, 0.f, 0.f, 0.f};
    f32x4 acc[4][4];
#pragma unroll
    for (int mt = 0; mt < 4; ++mt)
#pragma unroll
        for (int nt = 0; nt < 4; ++nt)
            acc[mt][nt] = zero4;

#define LOADREGS(kt)                                   \
    {   const float* p = sptr + (kt) * 128;            \
        st0 = *(const float4*)(p);                     \
        st1 = *(const float4*)(p + 4);                 \
        st2 = *(const float4*)(p + 8);                 \
        st3 = *(const float4*)(p + 12); }

#define CONVWRITE(buf)                                                     \
    {   union { unsigned short us[8]; uint4 u4; } pa, pb;                  \
        pa.us[0] = f32_to_bf16_rne(st0.x); pa.us[1] = f32_to_bf16_rne(st0.y); \
        pa.us[2] = f32_to_bf16_rne(st0.z); pa.us[3] = f32_to_bf16_rne(st0.w); \
        pa.us[4] = f32_to_bf16_rne(st1.x); pa.us[5] = f32_to_bf16_rne(st1.y); \
        pa.us[6] = f32_to_bf16_rne(st1.z); pa.us[7] = f32_to_bf16_rne(st1.w); \
        pb.us[0] = f32_to_bf16_rne(st2.x); pb.us[1] = f32_to_bf16_rne(st2.y); \
        pb.us[2] = f32_to_bf16_rne(st2.z); pb.us[3] = f32_to_bf16_rne(st2.w); \
        pb.us[4] = f32_to_bf16_rne(st3.x); pb.us[5] = f32_to_bf16_rne(st3.y); \
        pb.us[6] = f32_to_bf16_rne(st3.z); pb.us[7] = f32_to_bf16_rne(st3.w); \
        *(uint4*)(wr0 + (buf) * 16384) = pa.u4;                            \
        *(uint4*)(wr1 + (buf) * 16384) = pb.u4; }

#define STORE16(kt)                                                           \
    if (s16) {                                                                \
        union { _Float16 h[8]; uint4 u4; } pf0, pf1;                          \
        pf0.h[0] = (_Float16)st0.x; pf0.h[1] = (_Float16)st0.y;               \
        pf0.h[2] = (_Float16)st0.z; pf0.h[3] = (_Float16)st0.w;               \
        pf0.h[4] = (_Float16)st1.x; pf0.h[5] = (_Float16)st1.y;               \
        pf0.h[6] = (_Float16)st1.z; pf0.h[7] = (_Float16)st1.w;               \
        pf1.h[0] = (_Float16)st2.x; pf1.h[1] = (_Float16)st2.y;               \
        pf1.h[2] = (_Float16)st2.z; pf1.h[3] = (_Float16)st2.w;               \
        pf1.h[4] = (_Float16)st3.x; pf1.h[5] = (_Float16)st3.y;               \
        pf1.h[6] = (_Float16)st3.z; pf1.h[7] = (_Float16)st3.w;               \
        *(uint4*)(s16p + (kt) * 128)     = pf0.u4;                            \
        *(uint4*)(s16p + (kt) * 128 + 8) = pf1.u4;                            \
    }

#define COMPUTE(cur, kt)                                                      \
    _Pragma("unroll")                                                         \
    for (int ks4 = 0; ks4 < 4; ++ks4) {                                       \
        int gks = (kt) * 4 + ks4;                                             \
        bf16x8 af[4], bfb[4];                                                 \
        _Pragma("unroll")                                                     \
        for (int nt = 0; nt < 4; ++nt)                                        \
            bfb[nt] = *(const bf16x8*)(bpp + (nt * 32 + gks) * 512);          \
        _Pragma("unroll")                                                     \
        for (int mt = 0; mt < 4; ++mt) {                                      \
            int row = mt * 16 + l15;                                          \
            int byteoff = (cur) * 16384 + row * 256 +                         \
                          ((ks4 * 64 + l4 * 16) ^ ((row & 7) << 4));          \
            af[mt] = *(const bf16x8*)((const char*)A_lds + byteoff);          \
        }                                                                     \
        __builtin_amdgcn_s_setprio(1);                                        \
        _Pragma("unroll")                                                     \
        for (int mt = 0; mt < 4; ++mt)                                        \
            _Pragma("unroll")                                                 \
            for (int nt = 0; nt < 4; ++nt)                                    \
                acc[mt][nt] = __builtin_amdgcn_mfma_f32_16x16x32_bf16(        \
                    af[mt], bfb[nt], acc[mt][nt], 0, 0, 0);                   \
        __builtin_amdgcn_s_setprio(0);                                        \
    }

    // prologue: tile 0 staged to buf0 (+ f16 side copy)
    LOADREGS(0);
    CONVWRITE(0);
    STORE16(0);
    __syncthreads();

    int cur = 0;
#pragma unroll 1
    for (int kt = 0; kt < 7; ++kt) {
        LOADREGS(kt + 1);          // issue early; MFMAs below hide the HBM latency
        COMPUTE(cur, kt);
        CONVWRITE(cur ^ 1);        // counted vmcnt wait lands here; pa/pb die
        STORE16(kt + 1);           // f16 side copy from st regs; st die here
        __syncthreads();           // one barrier per K-tile
        cur ^= 1;
    }
    COMPUTE(cur, 7);               // tail tile

#undef LOADREGS
#undef CONVWRITE
#undef STORE16
#undef COMPUTE

    // epilogue: score[row] = sum_a tanh(y + x + b_g + b_s) * v[a], LDS-reduced
    float xbv[4], vv[4];
#pragma unroll
    for (int nt = 0; nt < 4; ++nt) {
        int a = wbase + nt * 16 + l15;
        xbv[nt] = xraw[bidx * 512 + a] + b_genes[a] + b_smiles[a];
        vv[nt]  = v[a];
    }
    float rs[4][4];
#pragma unroll
    for (int mt = 0; mt < 4; ++mt)
#pragma unroll
        for (int r = 0; r < 4; ++r)
            rs[mt][r] = 0.f;
#pragma unroll
    for (int mt = 0; mt < 4; ++mt)
#pragma unroll
        for (int nt = 0; nt < 4; ++nt)
#pragma unroll
            for (int r = 0; r < 4; ++r)
                rs[mt][r] += vv[nt] * fast_tanh(acc[mt][nt][r] + xbv[nt]);
#pragma unroll
    for (int mt = 0; mt < 4; ++mt)
#pragma unroll
        for (int r = 0; r < 4; ++r) {
            float s = rs[mt][r];
            s += __shfl_xor(s, 1);
            s += __shfl_xor(s, 2);
            s += __shfl_xor(s, 4);
            s += __shfl_xor(s, 8);
            rs[mt][r] = s;
        }
    if (l15 == 0) {
#pragma unroll
        for (int mt = 0; mt < 4; ++mt)
#pragma unroll
            for (int r = 0; r < 4; ++r)
                atomicAdd(&score_lds[mt * 16 + l4 * 4 + r], rs[mt][r]);
    }
    __syncthreads();
    if (tid < 64) scores[gm0 + tid] = score_lds[tid];
}

// K4 (f16 path): softmax recomputed per block from scores + weighted sum over
// the f16 smiles copy (half the HBM bytes of the f32 original).
__global__ void k4_soft16(const unsigned short* __restrict__ s16,
                          const float* __restrict__ scores,
                          float* __restrict__ out)
{
    __shared__ float redmax[4], redsum[4], al_lds[64];
    int bx = blockIdx.x;              // 1024 = 32 b * 32 t-chunks
    int b  = bx >> 5;
    int tc = bx & 31;
    int tid = threadIdx.x;            // 256
    int wid = tid >> 6;

    float sv[8];
    float mx = -1e30f;
#pragma unroll
    for (int i = 0; i < 8; ++i) {
        sv[i] = scores[b * 2048 + i * 256 + tid];
        mx = fmaxf(mx, sv[i]);
    }
#pragma unroll
    for (int m = 32; m >= 1; m >>= 1) mx = fmaxf(mx, __shfl_xor(mx, m));
    if ((tid & 63) == 0) redmax[wid] = mx;
    __syncthreads();
    mx = fmaxf(fmaxf(redmax[0], redmax[1]), fmaxf(redmax[2], redmax[3]));
    float zp = 0.f;
#pragma unroll
    for (int i = 0; i < 8; ++i) zp += __expf(sv[i] - mx);
#pragma unroll
    for (int m = 32; m >= 1; m >>= 1) zp += __shfl_xor(zp, m);
    if ((tid & 63) == 0) redsum[wid] = zp;
    __syncthreads();
    float invZ = 1.f / (redsum[0] + redsum[1] + redsum[2] + redsum[3]);
    if (tid < 64)
        al_lds[tid] = __expf(scores[b * 2048 + tc * 64 + tid] - mx) * invZ;
    __syncthreads();

    int h = tid * 4;                  // 256 threads -> 1024 h
    const unsigned short* sb = s16 + ((size_t)b * 2048 + tc * 64) * 1024;
    float4 acc = {0.f, 0.f, 0.f, 0.f};
#pragma unroll 4
    for (int t = 0; t < 64; ++t) {
        float a = al_lds[t];
        ushort4 u = *(const ushort4*)(sb + (size_t)t * 1024 + h);
        acc.x += a * f16b2f(u.x);
        acc.y += a * f16b2f(u.y);
        acc.z += a * f16b2f(u.z);
        acc.w += a * f16b2f(u.w);
    }
    float* o = out + b * 1024 + h;
    atomicAdd(o + 0, acc.x);
    atomicAdd(o + 1, acc.y);
    atomicAdd(o + 2, acc.z);
    atomicAdd(o + 3, acc.w);
}

// K4 (f32 fallback, used when ws_size can't hold the f16 copy)
__global__ void k4_soft(const float* __restrict__ smiles,
                        const float* __restrict__ scores,
                        float* __restrict__ out)
{
    __shared__ float redmax[4], redsum[4], al_lds[64];
    int bx = blockIdx.x;
    int b  = bx >> 5;
    int tc = bx & 31;
    int tid = threadIdx.x;
    int wid = tid >> 6;

    float sv[8];
    float mx = -1e30f;
#pragma unroll
    for (int i = 0; i < 8; ++i) {
        sv[i] = scores[b * 2048 + i * 256 + tid];
        mx = fmaxf(mx, sv[i]);
    }
#pragma unroll
    for (int m = 32; m >= 1; m >>= 1) mx = fmaxf(mx, __shfl_xor(mx, m));
    if ((tid & 63) == 0) redmax[wid] = mx;
    __syncthreads();
    mx = fmaxf(fmaxf(redmax[0], redmax[1]), fmaxf(redmax[2], redmax[3]));
    float zp = 0.f;
#pragma unroll
    for (int i = 0; i < 8; ++i) zp += __expf(sv[i] - mx);
#pragma unroll
    for (int m = 32; m >= 1; m >>= 1) zp += __shfl_xor(zp, m);
    if ((tid & 63) == 0) redsum[wid] = zp;
    __syncthreads();
    float invZ = 1.f / (redsum[0] + redsum[1] + redsum[2] + redsum[3]);
    if (tid < 64)
        al_lds[tid] = __expf(scores[b * 2048 + tc * 64 + tid] - mx) * invZ;
    __syncthreads();

    int h = tid * 4;
    const float* sb = smiles + ((size_t)b * 2048 + tc * 64) * 1024;
    float4 acc = {0.f, 0.f, 0.f, 0.f};
#pragma unroll 4
    for (int t = 0; t < 64; ++t) {
        float a = al_lds[t];
        float4 sv4 = *(const float4*)(sb + (size_t)t * 1024 + h);
        acc.x += a * sv4.x;
        acc.y += a * sv4.y;
        acc.z += a * sv4.z;
        acc.w += a * sv4.w;
    }
    float* o = out + b * 1024 + h;
    atomicAdd(o + 0, acc.x);
    atomicAdd(o + 1, acc.y);
    atomicAdd(o + 2, acc.z);
    atomicAdd(o + 3, acc.w);
}

extern "C" void kernel_launch(void* const* d_in, const int* in_sizes, int n_in,
                              void* d_out, int out_size, void* d_ws, size_t ws_size,
                              hipStream_t stream) {
    const float* genes    = (const float*)d_in[0];
    const float* smiles   = (const float*)d_in[1];
    const float* w_ngf    = (const float*)d_in[2];
    const float* w_genes  = (const float*)d_in[3];
    const float* b_genes  = (const float*)d_in[4];
    const float* w_smiles = (const float*)d_in[5];
    const float* b_smiles = (const float*)d_in[6];
    const float* v        = (const float*)d_in[7];
    float* out = (float*)d_out;

    char* ws = (char*)d_ws;
    unsigned short* Bp = (unsigned short*)(ws);                        // 1 MB packed B
    float* gc     = (float*)(ws + (1 << 20));                          // 256 KB
    float* x      = (float*)(ws + (1 << 20) + (256 << 10));            // 64 KB
    float* scores = (float*)(ws + (1 << 20) + (320 << 10));            // 256 KB

    // f16 smiles copy: 32*2048*1024*2 = 128 MB at offset 2 MB, if ws allows
    const size_t s16_off   = (size_t)2 << 20;
    const size_t s16_bytes = (size_t)32 * 2048 * 1024 * 2;
    bool use16 = ws_size >= s16_off + s16_bytes;
    unsigned short* s16 = use16 ? (unsigned short*)(ws + s16_off) : (unsigned short*)0;

    hipMemsetAsync(out, 0, (size_t)32 * 1024 * sizeof(float), stream);
    hipMemsetAsync(x, 0, (size_t)64 * 1024, stream);

    k0b_pack<<<1024, 64, 0, stream>>>(w_smiles, Bp);
    k1a_gc<<<256, 256, 0, stream>>>((const float4*)genes, w_ngf, gc);
    k1b_x<<<512, 256, 0, stream>>>(gc, w_genes, x);
    k2_scores<<<1024, 512, 0, stream>>>(smiles, Bp, x, b_genes, b_smiles, v,
                                        scores, s16);
    if (use16)
        k4_soft16<<<1024, 256, 0, stream>>>(s16, scores, out);
    else
        k4_soft<<<1024, 256, 0, stream>>>(smiles, scores, out);
}

// Round 11
// 171.317 us; speedup vs baseline: 1.0909x; 1.0909x over previous
//
#include <hip/hip_runtime.h>

// Shapes: genes[32][2048][4], smiles[32][2048][1024], w_ngf[4], w_genes[2048][512],
//         b_genes[512], w_smiles[1024][512], b_smiles[512], v[512] -> out[32][1024]

typedef __bf16 bf16_t;
typedef bf16_t bf16x8 __attribute__((ext_vector_type(8)));
typedef float f32x4 __attribute__((ext_vector_type(4)));

__device__ __forceinline__ unsigned short f32_to_bf16_rne(float f) {
    unsigned int u = __builtin_bit_cast(unsigned int, f);
    u = (u + 0x7FFFu + ((u >> 16) & 1u)) >> 16;
    return (unsigned short)u;
}

__device__ __forceinline__ float fast_tanh(float x) {
    float cx = fminf(fmaxf(x, -30.f), 30.f);
    float e = __expf(2.f * cx);
    return (e - 1.f) / (e + 1.f);
}

// global -> LDS DMA, 16B per lane, wave-uniform LDS base (HW adds lane*16).
#define GLL16(g, l)                                                        \
    __builtin_amdgcn_global_load_lds(                                      \
        (const __attribute__((address_space(1))) void*)(g),                \
        (__attribute__((address_space(3))) void*)(l), 16, 0, 0)

// frag-granule swizzle: granule g of frag ff -> spread low bits
__device__ __forceinline__ int swzg(int ff, int g) {
    return (g & 56) | ((g ^ (g >> 3) ^ ff) & 7);
}

// K0b: pack w_smiles [1024][512] f32 into FRAGMENT-MAJOR bf16 (16x16 frags).
// Bp[frag=atile*32+gks][lane][e] = w[gks*32 + (lane>>4)*8 + e][atile*16 + (lane&15)]
__global__ void k0b_pack(const float* __restrict__ w, unsigned short* __restrict__ Bp) {
    int bid  = blockIdx.x;        // 1024 = 32 atiles * 32 gks
    int lane = threadIdx.x;       // 64
    int atile = bid >> 5, gks = bid & 31;
    int col = atile * 16 + (lane & 15);
    int k0  = gks * 32 + (lane >> 4) * 8;
    unsigned short us[8];
#pragma unroll
    for (int e = 0; e < 8; ++e)
        us[e] = f32_to_bf16_rne(w[(size_t)(k0 + e) * 512 + col]);
    *(uint4*)(Bp + (size_t)bid * 512 + lane * 8) = *(const uint4*)us;
}

// K1a: gc[b][g] = dot(genes[b][g][0..3], w_ngf)
__global__ void k1a_gc(const float4* __restrict__ genes, const float* __restrict__ wngf,
                       float* __restrict__ gc) {
    int i = blockIdx.x * 256 + threadIdx.x;   // 65536 = 32*2048
    float4 g = genes[i];
    gc[i] = g.x * wngf[0] + g.y * wngf[1] + g.z * wngf[2] + g.w * wngf[3];
}

// K1b: x[b][a] += sum_{g in chunk} gc[b][g] * w_genes[g][a]   (x pre-zeroed)
__global__ void k1b_x(const float* __restrict__ gc, const float* __restrict__ wg,
                      float* __restrict__ x) {
    __shared__ float gcl[256];
    int bx = blockIdx.x;              // 512 = 32 b * 2 a-halves * 8 g-chunks
    int b = bx >> 4, ah = (bx >> 3) & 1, gch = bx & 7;
    int g0 = gch * 256;
    gcl[threadIdx.x] = gc[b * 2048 + g0 + threadIdx.x];
    __syncthreads();
    int a = ah * 256 + threadIdx.x;
    float s = 0.f;
#pragma unroll 8
    for (int g = 0; g < 256; ++g) s += gcl[g] * wg[(size_t)(g0 + g) * 512 + a];
    atomicAdd(&x[b * 512 + a], s);
}

// K2: fused GEMM + tanh + dot(v) -> scores.  NEW STRUCTURE:
//   1024 thr (16 waves, 2x8 wave grid), BM=128 x BN=512, BK=32.
//   A+B double-buffered in 80KB LDS, ONE barrier per K-tile.
//   B staged via global_load_lds straight from bf16 Bp (no regs, no cvt).
//   A reg-staged (1 float4/thread) + cvt on store path.
//   Frag-major LDS layouts: all LDS reads conflict-free.
//   B-L2 traffic halves vs BM=64 (512 blocks x 1MB = 512MB).
__global__ __launch_bounds__(1024, 4) void k2_scores(
    const float* __restrict__ smiles,
    const unsigned short* __restrict__ Bp,
    const float* __restrict__ xraw,
    const float* __restrict__ b_genes,
    const float* __restrict__ b_smiles,
    const float* __restrict__ v,
    float* __restrict__ scores)
{
    __shared__ char LDS[81920];      // A: 2x8KB @0, B: 2x32KB @16KB
    char* const Aq0 = LDS;
    char* const Aq1 = LDS + 8192;
    char* const Bq0 = LDS + 16384;
    char* const Bq1 = LDS + 49152;

    const int tid  = threadIdx.x;
    const int wave = tid >> 6;                   // 0..15
    const int lane = tid & 63;
    const int l15  = lane & 15;
    const int l4   = lane >> 4;
    const int wr   = wave >> 3;                  // 0..1  (64-row group)
    const int wc   = wave & 7;                   // 0..7  (64-col group)
    const int gm0  = blockIdx.x * 128;           // 512 blocks
    const int bidx = gm0 >> 11;

    // A staging: thread owns 4 consecutive f32 of the 128x32 tile
    const int srow = tid >> 3;                   // 0..127
    const int kq   = tid & 7;                    // k-quad: 4 floats at kq*4
    const float* sptr = smiles + (size_t)(gm0 + srow) * 1024 + kq * 4;
    const int aff  = srow >> 4;                  // A frag 0..7
    const int ag   = (srow & 15) + 16 * (kq >> 1);
    const int awoff = aff * 1024 + swzg(aff, ag) * 16 + (kq & 1) * 8;

    float4 st;
    f32x4 acc[4][4];
#pragma unroll
    for (int mt = 0; mt < 4; ++mt)
#pragma unroll
        for (int nt = 0; nt < 4; ++nt)
            acc[mt][nt] = f32x4{0.f, 0.f, 0.f, 0.f};

#define LOADA(kt)  { st = *(const float4*)(sptr + (kt) * 32); }

#define GLLB(kt, bq)                                                          \
    _Pragma("unroll")                                                         \
    for (int i = 0; i < 2; ++i) {                                             \
        int atile = wave * 2 + i;                                             \
        const char* g = (const char*)Bp +                                     \
            (((size_t)atile * 32 + (kt)) << 10) + lane * 16;                  \
        GLL16(g, (bq) + atile * 1024);                                        \
    }

#define CONVWRITE(aq)                                                         \
    {   union { unsigned short us[4]; uint2 u2; } p;                          \
        p.us[0] = f32_to_bf16_rne(st.x); p.us[1] = f32_to_bf16_rne(st.y);     \
        p.us[2] = f32_to_bf16_rne(st.z); p.us[3] = f32_to_bf16_rne(st.w);     \
        *(uint2*)((aq) + awoff) = p.u2; }

#define COMPUTE(aq, bq)                                                       \
    {   bf16x8 af[4], bfb[4];                                                 \
        _Pragma("unroll")                                                     \
        for (int nt = 0; nt < 4; ++nt)                                        \
            bfb[nt] = *(const bf16x8*)((bq) + (wc * 4 + nt) * 1024 + lane * 16); \
        _Pragma("unroll")                                                     \
        for (int mt = 0; mt < 4; ++mt) {                                      \
            int ff = wr * 4 + mt;                                             \
            af[mt] = *(const bf16x8*)((aq) + ff * 1024 + swzg(ff, lane) * 16); \
        }                                                                     \
        __builtin_amdgcn_s_setprio(1);                                        \
        _Pragma("unroll")                                                     \
        for (int mt = 0; mt < 4; ++mt)                                        \
            _Pragma("unroll")                                                 \
            for (int nt = 0; nt < 4; ++nt)                                    \
                acc[mt][nt] = __builtin_amdgcn_mfma_f32_16x16x32_bf16(        \
                    af[mt], bfb[nt], acc[mt][nt], 0, 0, 0);                   \
        __builtin_amdgcn_s_setprio(0);                                        \
    }

    // prologue: tile 0 into buffer 0
    LOADA(0);
    GLLB(0, Bq0);
    CONVWRITE(Aq0);
    __syncthreads();

#pragma unroll 1
    for (int kt = 0; kt < 32; ++kt) {
        char* aqc = (kt & 1) ? Aq1 : Aq0;
        char* bqc = (kt & 1) ? Bq1 : Bq0;
        char* aqn = (kt & 1) ? Aq0 : Aq1;
        char* bqn = (kt & 1) ? Bq0 : Bq1;
        if (kt < 31) {
            LOADA(kt + 1);         // A load issues first (oldest in vmcnt FIFO)
            GLLB(kt + 1, bqn);     // 2 gll after -> CONVWRITE waits vmcnt(2)
        }
        COMPUTE(aqc, bqc);         // MFMAs age the loads
        if (kt < 31) CONVWRITE(aqn);
        __syncthreads();           // one barrier per tile (gll mostly aged)
    }

#undef LOADA
#undef GLLB
#undef CONVWRITE
#undef COMPUTE

    // epilogue: score[row] = sum_a tanh(y + x + b_g + b_s) * v[a]
    // C layout (m89): row = base + l4*4 + r, col = base + l15
    float* score_f = (float*)LDS;    // reuse Aq0 (last tile used buf1)
    if (tid < 128) score_f[tid] = 0.f;
    __syncthreads();

    float xbv[4], vv[4];
#pragma unroll
    for (int nt = 0; nt < 4; ++nt) {
        int a = wc * 64 + nt * 16 + l15;
        xbv[nt] = xraw[bidx * 512 + a] + b_genes[a] + b_smiles[a];
        vv[nt]  = v[a];
    }
#pragma unroll
    for (int mt = 0; mt < 4; ++mt) {
        float rs[4];
#pragma unroll
        for (int r = 0; r < 4; ++r) rs[r] = 0.f;
#pragma unroll
        for (int nt = 0; nt < 4; ++nt)
#pragma unroll
            for (int r = 0; r < 4; ++r)
                rs[r] += vv[nt] * fast_tanh(acc[mt][nt][r] + xbv[nt]);
#pragma unroll
        for (int r = 0; r < 4; ++r) {
            float s = rs[r];
            s += __shfl_xor(s, 1);
            s += __shfl_xor(s, 2);
            s += __shfl_xor(s, 4);
            s += __shfl_xor(s, 8);
            if (l15 == 0)
                atomicAdd(&score_f[wr * 64 + mt * 16 + l4 * 4 + r], s);
        }
    }
    __syncthreads();
    if (tid < 128) scores[gm0 + tid] = score_f[tid];
}

// K4: softmax (recomputed per block from scores, deterministic) + weighted sum.
// out[b][h] += sum_{t in chunk} alpha[b][t] * smiles[b][t][h]; t-split x32.
__global__ void k4_soft(const float* __restrict__ smiles,
                        const float* __restrict__ scores,
                        float* __restrict__ out)
{
    __shared__ float redmax[4], redsum[4], al_lds[64];
    int bx = blockIdx.x;              // 1024 = 32 b * 32 t-chunks
    int b  = bx >> 5;
    int tc = bx & 31;
    int tid = threadIdx.x;            // 256
    int wid = tid >> 6;

    float sv[8];
    float mx = -1e30f;
#pragma unroll
    for (int i = 0; i < 8; ++i) {
        sv[i] = scores[b * 2048 + i * 256 + tid];
        mx = fmaxf(mx, sv[i]);
    }
#pragma unroll
    for (int m = 32; m >= 1; m >>= 1) mx = fmaxf(mx, __shfl_xor(mx, m));
    if ((tid & 63) == 0) redmax[wid] = mx;
    __syncthreads();
    mx = fmaxf(fmaxf(redmax[0], redmax[1]), fmaxf(redmax[2], redmax[3]));
    float zp = 0.f;
#pragma unroll
    for (int i = 0; i < 8; ++i) zp += __expf(sv[i] - mx);
#pragma unroll
    for (int m = 32; m >= 1; m >>= 1) zp += __shfl_xor(zp, m);
    if ((tid & 63) == 0) redsum[wid] = zp;
    __syncthreads();
    float invZ = 1.f / (redsum[0] + redsum[1] + redsum[2] + redsum[3]);
    if (tid < 64)
        al_lds[tid] = __expf(scores[b * 2048 + tc * 64 + tid] - mx) * invZ;
    __syncthreads();

    int h = tid * 4;                  // 256 threads -> 1024 h
    const float* sb = smiles + ((size_t)b * 2048 + tc * 64) * 1024;
    float4 acc = {0.f, 0.f, 0.f, 0.f};
#pragma unroll 4
    for (int t = 0; t < 64; ++t) {
        float a = al_lds[t];
        float4 sv4 = *(const float4*)(sb + (size_t)t * 1024 + h);
        acc.x += a * sv4.x;
        acc.y += a * sv4.y;
        acc.z += a * sv4.z;
        acc.w += a * sv4.w;
    }
    float* o = out + b * 1024 + h;
    atomicAdd(o + 0, acc.x);
    atomicAdd(o + 1, acc.y);
    atomicAdd(o + 2, acc.z);
    atomicAdd(o + 3, acc.w);
}

extern "C" void kernel_launch(void* const* d_in, const int* in_sizes, int n_in,
                              void* d_out, int out_size, void* d_ws, size_t ws_size,
                              hipStream_t stream) {
    const float* genes    = (const float*)d_in[0];
    const float* smiles   = (const float*)d_in[1];
    const float* w_ngf    = (const float*)d_in[2];
    const float* w_genes  = (const float*)d_in[3];
    const float* b_genes  = (const float*)d_in[4];
    const float* w_smiles = (const float*)d_in[5];
    const float* b_smiles = (const float*)d_in[6];
    const float* v        = (const float*)d_in[7];
    float* out = (float*)d_out;

    char* ws = (char*)d_ws;
    unsigned short* Bp = (unsigned short*)(ws);                        // 1 MB packed B
    float* gc     = (float*)(ws + (1 << 20));                          // 256 KB
    float* x      = (float*)(ws + (1 << 20) + (256 << 10));            // 64 KB
    float* scores = (float*)(ws + (1 << 20) + (320 << 10));            // 256 KB

    hipMemsetAsync(out, 0, (size_t)32 * 1024 * sizeof(float), stream);
    hipMemsetAsync(x, 0, (size_t)64 * 1024, stream);

    k0b_pack<<<1024, 64, 0, stream>>>(w_smiles, Bp);
    k1a_gc<<<256, 256, 0, stream>>>((const float4*)genes, w_ngf, gc);
    k1b_x<<<512, 256, 0, stream>>>(gc, w_genes, x);
    k2_scores<<<512, 1024, 0, stream>>>(smiles, Bp, x, b_genes, b_smiles, v, scores);
    k4_soft<<<1024, 256, 0, stream>>>(smiles, scores, out);
}